// Round 10
// baseline (426.872 us; speedup 1.0000x reference)
//
#include <hip/hip_runtime.h>
#include <hip/hip_bf16.h>

#define BATCH 16
#define NCAND 25200
#define NCLS 80
#define PREDC 85
#define KTOP 1000
#define MAXDET 300
#define CAP 2048
#define NBINS 1024
#define SROWS 64          // rows per k_score block
#define CONF 0.45f
#define HSCALE ((float)NBINS / (1.0f - 0.45f))
#define CNT_STRIDE 16     // ints; 64B between per-image counters

typedef unsigned long long ull;

// ------- K1: score + argmax class + xyxy box + histogram (single pred pass) -------
// 64 rows/block, 128 threads, 2 threads per row (40 classes each).
__global__ __launch_bounds__(128) void k_score(const float* __restrict__ pred,
                                               float* __restrict__ score,
                                               float* __restrict__ bx,
                                               int* __restrict__ cls,
                                               int* __restrict__ hist) {
    __shared__ float lds[SROWS * PREDC];   // 21,760 B -> 7 blocks/CU
    int tile = blockIdx.x;
    int tid = threadIdx.x;
    size_t base = (size_t)tile * (SROWS * PREDC);
    const float4* src4 = (const float4*)(pred + base);
    float4* l4 = (float4*)lds;
    const int NV4 = SROWS * PREDC / 4;  // 1360
    for (int k = tid; k < NV4; k += 128) l4[k] = src4[k];
    __syncthreads();
    int r = tid >> 1, h = tid & 1;
    const float* row = lds + r * PREDC;
    float obj = row[4];
    float best = -1.0f; int bj = 0;
    int c0 = h * 40;
    #pragma unroll 8
    for (int c = 0; c < 40; ++c) {
        float v = row[5 + c0 + c] * obj;
        if (v > best) { best = v; bj = c0 + c; }   // first-max within half
    }
    // merge halves: strict > keeps lower-index half on ties (first-max overall)
    float obest = __shfl_xor(best, 1);
    int obj2 = __shfl_xor(bj, 1);
    if (h == 0) {
        if (obest > best) { best = obest; bj = obj2; }
    } else {
        if (best > obest) { /* keep */ } else { best = obest; bj = obj2; }
    }
    if (h == 0) {
        bool valid = (obj > CONF) && (best > CONF);
        float s = valid ? best : -1.0f;
        int grow = tile * SROWS + r;
        score[grow] = s;
        cls[grow] = bj;
        float cx = row[0], cy = row[1], w = row[2], hh = row[3];
        ((float4*)bx)[grow] = make_float4(cx - w * 0.5f, cy - hh * 0.5f,
                                          cx + w * 0.5f, cy + hh * 0.5f);
        if (s > CONF) {
            int b = grow / NCAND;
            int bin = (int)((s - CONF) * HSCALE);
            bin = bin < 0 ? 0 : (bin > NBINS - 1 ? NBINS - 1 : bin);
            atomicAdd(&hist[b * NBINS + bin], 1);
        }
    }
}

// ---- K2: per-image T-from-hist + gather + hybrid bitonic sort + emit top-K ----
__device__ __forceinline__ void cmpx(ull& r, ull p, bool keepMin) {
    ull mn = r < p ? r : p;
    ull mx = r < p ? p : r;
    r = keepMin ? mn : mx;
}

__global__ __launch_bounds__(1024) void k_topk(const float* __restrict__ score,
                                               const float* __restrict__ bx,
                                               const int* __restrict__ cls,
                                               const int* __restrict__ hist_g,
                                               int* __restrict__ topidx,
                                               float* __restrict__ topsc,
                                               int* __restrict__ topcls,
                                               float* __restrict__ boxes,
                                               int* __restrict__ cnt) {
    __shared__ int hist[NBINS];        // 4 KB
    __shared__ ull sbuf[CAP];          // 16 KB
    __shared__ int s_T, s_base;
    int b = blockIdx.x, tid = threadIdx.x;
    int lane = tid & 63;
    const float* sc = score + (size_t)b * NCAND;
    const float4* sc4 = (const float4*)sc;
    const int NF4 = NCAND / 4;         // 6300
    hist[tid] = hist_g[b * NBINS + tid];
    if (tid == 0) { s_T = 0; s_base = 0; }
    __syncthreads();
    // suffix scan (Hillis-Steele, 1 bin/thread)
    for (int off = 1; off < NBINS; off <<= 1) {
        int v = (tid + off < NBINS) ? hist[tid + off] : 0;
        __syncthreads();
        hist[tid] += v;
        __syncthreads();
    }
    {
        int S = hist[tid];
        int Sn = (tid + 1 < NBINS) ? hist[tid + 1] : 0;
        if (S >= KTOP && Sn < KTOP) s_T = tid;   // unique (suffix monotone)
    }
    sbuf[tid] = ~0ULL;
    sbuf[tid + 1024] = ~0ULL;
    __syncthreads();
    int T = s_T;
    // gather survivors into LDS (wave-compaction, LDS-atomic base)
    for (int f = tid; f < NF4; f += 1024) {
        float4 v4 = sc4[f];
        float vs[4] = {v4.x, v4.y, v4.z, v4.w};
        #pragma unroll
        for (int e = 0; e < 4; ++e) {
            float s = vs[e];
            bool want = false;
            if (s > CONF) {
                int bin = (int)((s - CONF) * HSCALE);
                bin = bin < 0 ? 0 : (bin > NBINS - 1 ? NBINS - 1 : bin);
                want = (bin >= T);
            }
            ull m = __ballot(want);
            int wb = 0;
            if (lane == 0 && m) wb = atomicAdd(&s_base, (int)__popcll(m));
            wb = __shfl(wb, 0);
            if (want) {
                int pos = wb + (int)__popcll(m & ((1ULL << lane) - 1ULL));
                if (pos < CAP) {
                    unsigned sb2 = __float_as_uint(s);
                    sbuf[pos] = ((ull)(~sb2) << 32) | (unsigned)(f * 4 + e);
                }
            }
        }
    }
    __syncthreads();
    int C2 = s_base; if (C2 > CAP) C2 = CAP;
    // hybrid bitonic sort of 2048 keys: regs r0,r1; shfl for j<=32, LDS for j>=64
    ull r0 = sbuf[tid];
    ull r1 = sbuf[tid + 1024];
    int t2 = tid + 1024;
    #pragma unroll
    for (unsigned k = 2; k <= 64; k <<= 1) {
        #pragma unroll
        for (unsigned j = k >> 1; j > 0; j >>= 1) {
            ull p0 = __shfl_xor(r0, (int)j);
            ull p1 = __shfl_xor(r1, (int)j);
            bool amLow = ((tid & j) == 0);
            cmpx(r0, p0, amLow == ((tid & k) == 0));
            cmpx(r1, p1, amLow == ((t2 & k) == 0));
        }
    }
    #pragma unroll
    for (unsigned k = 128; k <= 1024; k <<= 1) {
        #pragma unroll
        for (unsigned j = k >> 1; j >= 64; j >>= 1) {
            sbuf[tid] = r0; sbuf[t2] = r1;
            __syncthreads();
            ull p0 = sbuf[tid ^ j];
            ull p1 = sbuf[t2 ^ j];
            cmpx(r0, p0, ((tid & j) == 0) == ((tid & k) == 0));
            cmpx(r1, p1, ((t2 & j) == 0) == ((t2 & k) == 0));
            __syncthreads();
        }
        #pragma unroll
        for (unsigned j = 32; j > 0; j >>= 1) {
            ull p0 = __shfl_xor(r0, (int)j);
            ull p1 = __shfl_xor(r1, (int)j);
            bool amLow = ((tid & j) == 0);
            cmpx(r0, p0, amLow == ((tid & k) == 0));
            cmpx(r1, p1, amLow == ((t2 & k) == 0));
        }
    }
    {
        if (r1 < r0) { ull t = r0; r0 = r1; r1 = t; }   // k=2048, j=1024 in-thread
        #pragma unroll
        for (unsigned j = 512; j >= 64; j >>= 1) {
            sbuf[tid] = r0; sbuf[t2] = r1;
            __syncthreads();
            ull p0 = sbuf[tid ^ j];
            ull p1 = sbuf[t2 ^ j];
            cmpx(r0, p0, ((tid & j) == 0));
            cmpx(r1, p1, ((t2 & j) == 0));
            __syncthreads();
        }
        #pragma unroll
        for (unsigned j = 32; j > 0; j >>= 1) {
            ull p0 = __shfl_xor(r0, (int)j);
            ull p1 = __shfl_xor(r1, (int)j);
            bool amLow = ((tid & j) == 0);
            cmpx(r0, p0, amLow);
            cmpx(r1, p1, amLow);
        }
    }
    // emit top-K from r0 (ranks 0..1023)
    if (tid < KTOP) {
        int o = b * KTOP + tid;
        if (tid < C2) {
            int n = (int)(r0 & 0xFFFFFFFFULL);
            float s = __uint_as_float(~(unsigned)(r0 >> 32));
            topidx[o] = n;
            topsc[o] = s;
            topcls[o] = cls[b * NCAND + n];
            ((float4*)boxes)[o] = ((const float4*)bx)[b * NCAND + n];
        } else {
            topidx[o] = 0; topsc[o] = -1.0f; topcls[o] = 0;
            ((float4*)boxes)[o] = make_float4(0.f, 0.f, 0.f, 0.f);
        }
    }
    if (tid == 0) cnt[b * CNT_STRIDE] = C2;
}

// ---- on-the-fly IoU word: rows vs cols [w*64, w*64+64), bits only where j>r ----
__device__ __forceinline__ ull iou_word(const float4* __restrict__ bxl, int r, int w) {
    #pragma clang fp contract(off)
    int j0 = w * 64;
    if (j0 + 63 <= r) return 0ULL;           // whole word strictly j<=r
    float4 A = bxl[r];
    float areaA = (A.z - A.x) * (A.w - A.y);
    ull word = 0;
    #pragma unroll 4
    for (int j = j0; j < j0 + 64; ++j) {     // bxl padded to 1024 (zeros -> iou 0)
        float4 Bb = bxl[j];
        float areaB = (Bb.z - Bb.x) * (Bb.w - Bb.y);
        float lx = fmaxf(A.x, Bb.x), ly = fmaxf(A.y, Bb.y);
        float rx = fminf(A.z, Bb.z), ry = fminf(A.w, Bb.w);
        float ww = rx - lx; ww = ww > 0.f ? ww : 0.f;
        float hh = ry - ly; hh = hh > 0.f ? hh : 0.f;
        float inter = ww * hh;
        float denom = ((areaA + areaB) - inter) + 1e-9f;
        float iou = inter / denom;
        if (j > r && iou > 0.45f) word |= 1ULL << (j - j0);
    }
    return word;
}

// ------ K3: fused IoU + block-NMS (staging waves compute M) + top-300 outputs ------
__global__ __launch_bounds__(1024) void k_nms_out(const int* __restrict__ cnt,
                                                  const float* __restrict__ logits,
                                                  const int* __restrict__ topidx,
                                                  const float* __restrict__ topsc,
                                                  const int* __restrict__ topcls,
                                                  const float* __restrict__ boxes,
                                                  float* __restrict__ out) {
    __shared__ float4 bxl[1024];      // 16 KB (rows 1000..1023 zero)
    __shared__ ull buf[2][64 * 17];   // 17,408 B, stride-17 pad
    __shared__ ull s_keep[16];
    __shared__ int kept_r[MAXDET];
    __shared__ int kept_n[MAXDET];
    __shared__ int s_kc;
    int b = blockIdx.x, tid = threadIdx.x;
    int kc0 = cnt[b * CNT_STRIDE]; if (kc0 > KTOP) kc0 = KTOP;
    bxl[tid] = (tid < KTOP) ? ((const float4*)boxes)[b * KTOP + tid]
                            : make_float4(0.f, 0.f, 0.f, 0.f);
    __syncthreads();
    // compute block rb=0 (1024 words, one per thread)
    buf[0][(tid >> 4) * 17 + (tid & 15)] = iou_word(bxl, tid >> 4, tid & 15);
    __syncthreads();
    ull supp;
    {
        int w = tid & 15, lo = w * 64;
        if (kc0 <= lo) supp = ~0ULL;
        else if (kc0 >= lo + 64) supp = 0ULL;
        else supp = (~0ULL) << (kc0 - lo);
    }
    for (int rb = 0; rb < 16; ++rb) {
        int cur = rb & 1, nxt = cur ^ 1;
        if (tid >= 64) {
            if (rb < 15) {
                // 960 threads compute the next 1024-word block
                for (int u = tid - 64; u < 1024; u += 960)
                    buf[nxt][(u >> 4) * 17 + (u & 15)] =
                        iou_word(bxl, (rb + 1) * 64 + (u >> 4), u & 15);
            }
        } else {
            int l = tid, w = l & 15, q = l >> 4;
            const ull* B = buf[cur];
            ull drow = B[l * 17 + rb];
            ull crow[16];
            #pragma unroll
            for (int k = 0; k < 16; ++k) crow[k] = B[(q + 4 * k) * 17 + w];
            // merged supp word rb -> wave-uniform scalar
            int slo = (int)(supp & 0xffffffffULL);
            int shi = (int)(supp >> 32);
            unsigned rlo = (unsigned)__builtin_amdgcn_readlane(slo, rb)
                         | (unsigned)__builtin_amdgcn_readlane(slo, rb + 16)
                         | (unsigned)__builtin_amdgcn_readlane(slo, rb + 32)
                         | (unsigned)__builtin_amdgcn_readlane(slo, rb + 48);
            unsigned rhi = (unsigned)__builtin_amdgcn_readlane(shi, rb)
                         | (unsigned)__builtin_amdgcn_readlane(shi, rb + 16)
                         | (unsigned)__builtin_amdgcn_readlane(shi, rb + 32)
                         | (unsigned)__builtin_amdgcn_readlane(shi, rb + 48);
            ull removed = ((ull)rhi << 32) | rlo;
            int dlo_v = (int)(drow & 0xffffffffULL);
            int dhi_v = (int)(drow >> 32);
            // 64-step serial resolve on wave-uniform scalars (SALU chain)
            #pragma unroll
            for (int s = 0; s < 64; ++s) {
                unsigned dl = (unsigned)__builtin_amdgcn_readlane(dlo_v, s);
                unsigned dh = (unsigned)__builtin_amdgcn_readlane(dhi_v, s);
                ull d64 = ((ull)dh << 32) | dl;
                if (!((removed >> s) & 1ULL)) removed |= d64;
            }
            // dense parallel apply
            ull acc = 0;
            #pragma unroll
            for (int k = 0; k < 16; ++k) {
                int r = q + 4 * k;
                if (!((removed >> r) & 1ULL)) acc |= crow[k];
            }
            supp |= acc;
        }
        __syncthreads();
    }
    if (tid < 64) {
        supp |= __shfl_xor(supp, 16);
        supp |= __shfl_xor(supp, 32);
        if (tid < 16) s_keep[tid] = ~supp;
    }
    __syncthreads();
    if (tid < 16) {
        int pre = 0;
        for (int u = 0; u < tid; ++u) pre += __popcll(s_keep[u]);
        ull wv = s_keep[tid];
        int rank = pre;
        while (wv) {
            int bit = __builtin_ctzll(wv);
            if (rank < MAXDET) kept_r[rank] = tid * 64 + bit;
            rank++;
            wv &= wv - 1;
        }
        if (tid == 15) s_kc = rank < MAXDET ? rank : MAXDET;
    }
    __syncthreads();
    int kc = s_kc;
    if (tid < MAXDET && tid < kc) kept_n[tid] = topidx[b * KTOP + kept_r[tid]];
    __syncthreads();
    // ---- output phase (all 1024 threads) ----
    float* det = out;                                        // [16][300][6]
    float* mask_o = out + BATCH * MAXDET * 6;                // [16][300]
    float* lgo = out + BATCH * MAXDET * 6 + BATCH * MAXDET;  // [16][300][80]
    for (int idx = tid; idx < MAXDET * 6; idx += 1024) {
        int s = idx / 6, col = idx % 6;
        float v = 0.f;
        if (s < kc) {
            int o = b * KTOP + kept_r[s];
            if (col < 4) v = boxes[o * 4 + col];
            else if (col == 4) v = topsc[o];
            else v = (float)topcls[o];
        }
        det[b * MAXDET * 6 + idx] = v;
    }
    for (int s = tid; s < MAXDET; s += 1024)
        mask_o[b * MAXDET + s] = (s < kc) ? 1.0f : 0.0f;
    float4* lgo4 = (float4*)(lgo + (size_t)b * MAXDET * NCLS);
    const float4* lg4 = (const float4*)logits;
    for (int idx = tid; idx < MAXDET * (NCLS / 4); idx += 1024) {
        int s = idx / (NCLS / 4), cc = idx % (NCLS / 4);
        float4 v = make_float4(0.f, 0.f, 0.f, 0.f);
        if (s < kc) v = lg4[((size_t)b * NCAND + kept_n[s]) * (NCLS / 4) + cc];
        lgo4[idx] = v;
    }
}

extern "C" void kernel_launch(void* const* d_in, const int* in_sizes, int n_in,
                              void* d_out, int out_size, void* d_ws, size_t ws_size,
                              hipStream_t stream) {
    (void)in_sizes; (void)n_in; (void)out_size; (void)ws_size;
    const float* pred = (const float*)d_in[0];
    const float* logits = (const float*)d_in[1];
    float* out = (float*)d_out;
    char* ws = (char*)d_ws;

    // workspace layout (bytes)
    float* score  = (float*)(ws + 0);                    // 1,612,800
    float* bx     = (float*)(ws + 1612800);              // 6,451,200 (16B aligned)
    int*   cls    = (int*)(ws + 8064000);                // 1,612,800
    int*   hist   = (int*)(ws + 9676800);                // 65,536
    int*   cnt    = (int*)(ws + 9742336);                // 1,024 (16 imgs x 64B)
    int*   topidx = (int*)(ws + 9743360);                // 64,000
    float* topsc  = (float*)(ws + 9807360);              // 64,000
    int*   topcls = (int*)(ws + 9871360);                // 64,000
    float* boxes  = (float*)(ws + 9935360);              // 256,000 (16B aligned)
                                                         // total 10,191,360

    const int nrows = BATCH * NCAND;                     // 403200
    hipMemsetAsync(hist, 0, BATCH * NBINS * sizeof(int), stream);
    k_score<<<nrows / SROWS, 128, 0, stream>>>(pred, score, bx, cls, hist);
    k_topk<<<BATCH, 1024, 0, stream>>>(score, bx, cls, hist, topidx, topsc, topcls, boxes, cnt);
    k_nms_out<<<BATCH, 1024, 0, stream>>>(cnt, logits, topidx, topsc, topcls, boxes, out);
}

// Round 11
// 138.341 us; speedup vs baseline: 3.0857x; 3.0857x over previous
//
#include <hip/hip_runtime.h>
#include <hip/hip_bf16.h>

#define BATCH 16
#define NCAND 25200
#define NCLS 80
#define PREDC 85
#define KTOP 1000
#define MAXDET 300
#define CAP 2048
#define NBINS 1024
#define SROWS 64          // rows per k_score block
#define CONF 0.45f
#define HSCALE ((float)NBINS / (1.0f - 0.45f))
#define CNT_STRIDE 16     // ints; 64B between per-image counters

typedef unsigned long long ull;

// ------- K1: score + argmax class + xyxy box + histogram (single pred pass) -------
// 64 rows/block, 128 threads, 2 threads per row (40 classes each).
__global__ __launch_bounds__(128) void k_score(const float* __restrict__ pred,
                                               float* __restrict__ score,
                                               float* __restrict__ bx,
                                               int* __restrict__ cls,
                                               int* __restrict__ hist) {
    __shared__ float lds[SROWS * PREDC];   // 21,760 B -> 7 blocks/CU
    int tile = blockIdx.x;
    int tid = threadIdx.x;
    size_t base = (size_t)tile * (SROWS * PREDC);
    const float4* src4 = (const float4*)(pred + base);
    float4* l4 = (float4*)lds;
    const int NV4 = SROWS * PREDC / 4;  // 1360
    for (int k = tid; k < NV4; k += 128) l4[k] = src4[k];
    __syncthreads();
    int r = tid >> 1, h = tid & 1;
    const float* row = lds + r * PREDC;
    float obj = row[4];
    float best = -1.0f; int bj = 0;
    int c0 = h * 40;
    #pragma unroll 8
    for (int c = 0; c < 40; ++c) {
        float v = row[5 + c0 + c] * obj;
        if (v > best) { best = v; bj = c0 + c; }   // first-max within half
    }
    // merge halves: strict > keeps lower-index half on ties (first-max overall)
    float obest = __shfl_xor(best, 1);
    int obj2 = __shfl_xor(bj, 1);
    if (h == 0) {
        if (obest > best) { best = obest; bj = obj2; }
    } else {
        if (best > obest) { /* keep */ } else { best = obest; bj = obj2; }
    }
    if (h == 0) {
        bool valid = (obj > CONF) && (best > CONF);
        float s = valid ? best : -1.0f;
        int grow = tile * SROWS + r;
        score[grow] = s;
        cls[grow] = bj;
        float cx = row[0], cy = row[1], w = row[2], hh = row[3];
        ((float4*)bx)[grow] = make_float4(cx - w * 0.5f, cy - hh * 0.5f,
                                          cx + w * 0.5f, cy + hh * 0.5f);
        if (s > CONF) {
            int b = grow / NCAND;
            int bin = (int)((s - CONF) * HSCALE);
            bin = bin < 0 ? 0 : (bin > NBINS - 1 ? NBINS - 1 : bin);
            atomicAdd(&hist[b * NBINS + bin], 1);
        }
    }
}

// ---- K2: per-image T-from-hist + gather + hybrid bitonic sort + emit top-K ----
__device__ __forceinline__ void cmpx(ull& r, ull p, bool keepMin) {
    ull mn = r < p ? r : p;
    ull mx = r < p ? p : r;
    r = keepMin ? mn : mx;
}

__global__ __launch_bounds__(1024) void k_topk(const float* __restrict__ score,
                                               const float* __restrict__ bx,
                                               const int* __restrict__ cls,
                                               const int* __restrict__ hist_g,
                                               int* __restrict__ topidx,
                                               float* __restrict__ topsc,
                                               int* __restrict__ topcls,
                                               float* __restrict__ boxes,
                                               int* __restrict__ cnt) {
    __shared__ int hist[NBINS];        // 4 KB
    __shared__ ull sbuf[CAP];          // 16 KB
    __shared__ int s_T, s_base;
    int b = blockIdx.x, tid = threadIdx.x;
    int lane = tid & 63;
    const float* sc = score + (size_t)b * NCAND;
    const float4* sc4 = (const float4*)sc;
    const int NF4 = NCAND / 4;         // 6300
    hist[tid] = hist_g[b * NBINS + tid];
    if (tid == 0) { s_T = 0; s_base = 0; }
    __syncthreads();
    // suffix scan (Hillis-Steele, 1 bin/thread)
    for (int off = 1; off < NBINS; off <<= 1) {
        int v = (tid + off < NBINS) ? hist[tid + off] : 0;
        __syncthreads();
        hist[tid] += v;
        __syncthreads();
    }
    {
        int S = hist[tid];
        int Sn = (tid + 1 < NBINS) ? hist[tid + 1] : 0;
        if (S >= KTOP && Sn < KTOP) s_T = tid;   // unique (suffix monotone)
    }
    sbuf[tid] = ~0ULL;
    sbuf[tid + 1024] = ~0ULL;
    __syncthreads();
    int T = s_T;
    // gather survivors into LDS (wave-compaction, LDS-atomic base)
    for (int f = tid; f < NF4; f += 1024) {
        float4 v4 = sc4[f];
        float vs[4] = {v4.x, v4.y, v4.z, v4.w};
        #pragma unroll
        for (int e = 0; e < 4; ++e) {
            float s = vs[e];
            bool want = false;
            if (s > CONF) {
                int bin = (int)((s - CONF) * HSCALE);
                bin = bin < 0 ? 0 : (bin > NBINS - 1 ? NBINS - 1 : bin);
                want = (bin >= T);
            }
            ull m = __ballot(want);
            int wb = 0;
            if (lane == 0 && m) wb = atomicAdd(&s_base, (int)__popcll(m));
            wb = __shfl(wb, 0);
            if (want) {
                int pos = wb + (int)__popcll(m & ((1ULL << lane) - 1ULL));
                if (pos < CAP) {
                    unsigned sb2 = __float_as_uint(s);
                    sbuf[pos] = ((ull)(~sb2) << 32) | (unsigned)(f * 4 + e);
                }
            }
        }
    }
    __syncthreads();
    int C2 = s_base; if (C2 > CAP) C2 = CAP;
    // hybrid bitonic sort of 2048 keys: regs r0,r1; shfl for j<=32, LDS for j>=64
    ull r0 = sbuf[tid];
    ull r1 = sbuf[tid + 1024];
    int t2 = tid + 1024;
    #pragma unroll
    for (unsigned k = 2; k <= 64; k <<= 1) {
        #pragma unroll
        for (unsigned j = k >> 1; j > 0; j >>= 1) {
            ull p0 = __shfl_xor(r0, (int)j);
            ull p1 = __shfl_xor(r1, (int)j);
            bool amLow = ((tid & j) == 0);
            cmpx(r0, p0, amLow == ((tid & k) == 0));
            cmpx(r1, p1, amLow == ((t2 & k) == 0));
        }
    }
    #pragma unroll
    for (unsigned k = 128; k <= 1024; k <<= 1) {
        #pragma unroll
        for (unsigned j = k >> 1; j >= 64; j >>= 1) {
            sbuf[tid] = r0; sbuf[t2] = r1;
            __syncthreads();
            ull p0 = sbuf[tid ^ j];
            ull p1 = sbuf[t2 ^ j];
            cmpx(r0, p0, ((tid & j) == 0) == ((tid & k) == 0));
            cmpx(r1, p1, ((t2 & j) == 0) == ((t2 & k) == 0));
            __syncthreads();
        }
        #pragma unroll
        for (unsigned j = 32; j > 0; j >>= 1) {
            ull p0 = __shfl_xor(r0, (int)j);
            ull p1 = __shfl_xor(r1, (int)j);
            bool amLow = ((tid & j) == 0);
            cmpx(r0, p0, amLow == ((tid & k) == 0));
            cmpx(r1, p1, amLow == ((t2 & k) == 0));
        }
    }
    {
        if (r1 < r0) { ull t = r0; r0 = r1; r1 = t; }   // k=2048, j=1024 in-thread
        #pragma unroll
        for (unsigned j = 512; j >= 64; j >>= 1) {
            sbuf[tid] = r0; sbuf[t2] = r1;
            __syncthreads();
            ull p0 = sbuf[tid ^ j];
            ull p1 = sbuf[t2 ^ j];
            cmpx(r0, p0, ((tid & j) == 0));
            cmpx(r1, p1, ((t2 & j) == 0));
            __syncthreads();
        }
        #pragma unroll
        for (unsigned j = 32; j > 0; j >>= 1) {
            ull p0 = __shfl_xor(r0, (int)j);
            ull p1 = __shfl_xor(r1, (int)j);
            bool amLow = ((tid & j) == 0);
            cmpx(r0, p0, amLow);
            cmpx(r1, p1, amLow);
        }
    }
    // emit top-K from r0 (ranks 0..1023)
    if (tid < KTOP) {
        int o = b * KTOP + tid;
        if (tid < C2) {
            int n = (int)(r0 & 0xFFFFFFFFULL);
            float s = __uint_as_float(~(unsigned)(r0 >> 32));
            topidx[o] = n;
            topsc[o] = s;
            topcls[o] = cls[b * NCAND + n];
            ((float4*)boxes)[o] = ((const float4*)bx)[b * NCAND + n];
        } else {
            topidx[o] = 0; topsc[o] = -1.0f; topcls[o] = 0;
            ((float4*)boxes)[o] = make_float4(0.f, 0.f, 0.f, 0.f);
        }
    }
    if (tid == 0) cnt[b * CNT_STRIDE] = C2;
}

// ---------------- K3: IoU bitmask (j>i, iou>thr), full-grid parallel ----------------
__global__ __launch_bounds__(256) void k_iou(const float* __restrict__ boxes,
                                             ull* __restrict__ M) {
    #pragma clang fp contract(off)
    int g = blockIdx.x * 256 + threadIdx.x;   // 16*1000*16 = 256000
    int w = g & 15;
    int bi = g >> 4;                          // 0..15999
    int i = bi % KTOP;
    int b = bi / KTOP;
    int j0 = w * 64;
    if (j0 + 63 <= i) {                       // whole block strictly j<=i -> zero
        M[(size_t)bi * 16 + w] = 0ULL;
        return;
    }
    const float4* bxp = (const float4*)boxes + (size_t)b * KTOP;
    float4 A = bxp[i];
    float areaA = (A.z - A.x) * (A.w - A.y);
    ull word = 0;
    int jend = j0 + 64; if (jend > KTOP) jend = KTOP;
    #pragma unroll 4
    for (int j = j0; j < jend; ++j) {
        float4 Bb = bxp[j];
        float areaB = (Bb.z - Bb.x) * (Bb.w - Bb.y);
        float lx = fmaxf(A.x, Bb.x), ly = fmaxf(A.y, Bb.y);
        float rx = fminf(A.z, Bb.z), ry = fminf(A.w, Bb.w);
        float ww = rx - lx; ww = ww > 0.f ? ww : 0.f;
        float hh = ry - ly; hh = hh > 0.f ? hh : 0.f;
        float inter = ww * hh;
        float denom = ((areaA + areaB) - inter) + 1e-9f;
        float iou = inter / denom;
        if (j > i && iou > 0.45f) word |= 1ULL << (j - j0);
    }
    M[(size_t)bi * 16 + w] = word;
}

// ------ K4: block-NMS (staged dbuf + wave0 scalar resolve) + top-300 outputs ------
__global__ __launch_bounds__(1024) void k_nms_out(const ull* __restrict__ M,
                                                  const int* __restrict__ cnt,
                                                  const float* __restrict__ logits,
                                                  const int* __restrict__ topidx,
                                                  const float* __restrict__ topsc,
                                                  const int* __restrict__ topcls,
                                                  const float* __restrict__ boxes,
                                                  float* __restrict__ out) {
    __shared__ ull buf[2][64 * 17];   // stride-17 pad: <=4-way bank conflict
    __shared__ ull s_keep[16];
    __shared__ int kept_r[MAXDET];
    __shared__ int kept_n[MAXDET];
    __shared__ int s_kc;
    int b = blockIdx.x, tid = threadIdx.x;
    int kc0 = cnt[b * CNT_STRIDE]; if (kc0 > KTOP) kc0 = KTOP;
    const ull* Mb = M + (size_t)b * KTOP * 16;
    // stage block 0 (all 1024 threads, coalesced)
    buf[0][(tid >> 4) * 17 + (tid & 15)] = Mb[tid];
    __syncthreads();
    ull supp;
    {
        int w = tid & 15, lo = w * 64;
        if (kc0 <= lo) supp = ~0ULL;
        else if (kc0 >= lo + 64) supp = 0ULL;
        else supp = (~0ULL) << (kc0 - lo);
    }
    for (int rb = 0; rb < 16; ++rb) {
        int cur = rb & 1, nxt = cur ^ 1;
        if (tid >= 64) {
            if (rb < 15) {
                // 960 threads stage the next 1024-word block
                for (int u = tid - 64; u < 1024; u += 960) {
                    int idx = (rb + 1) * 1024 + u;
                    int g = idx < 16000 ? idx : 15999;   // tail masked by 'removed'
                    buf[nxt][(u >> 4) * 17 + (u & 15)] = Mb[g];
                }
            }
        } else {
            int l = tid, w = l & 15, q = l >> 4;
            const ull* B = buf[cur];
            ull drow = B[l * 17 + rb];
            ull crow[16];
            #pragma unroll
            for (int k = 0; k < 16; ++k) crow[k] = B[(q + 4 * k) * 17 + w];
            // merged supp word rb -> wave-uniform scalar
            int slo = (int)(supp & 0xffffffffULL);
            int shi = (int)(supp >> 32);
            unsigned rlo = (unsigned)__builtin_amdgcn_readlane(slo, rb)
                         | (unsigned)__builtin_amdgcn_readlane(slo, rb + 16)
                         | (unsigned)__builtin_amdgcn_readlane(slo, rb + 32)
                         | (unsigned)__builtin_amdgcn_readlane(slo, rb + 48);
            unsigned rhi = (unsigned)__builtin_amdgcn_readlane(shi, rb)
                         | (unsigned)__builtin_amdgcn_readlane(shi, rb + 16)
                         | (unsigned)__builtin_amdgcn_readlane(shi, rb + 32)
                         | (unsigned)__builtin_amdgcn_readlane(shi, rb + 48);
            ull removed = ((ull)rhi << 32) | rlo;
            int dlo_v = (int)(drow & 0xffffffffULL);
            int dhi_v = (int)(drow >> 32);
            // 64-step serial resolve on wave-uniform scalars (SALU chain)
            #pragma unroll
            for (int s = 0; s < 64; ++s) {
                unsigned dl = (unsigned)__builtin_amdgcn_readlane(dlo_v, s);
                unsigned dh = (unsigned)__builtin_amdgcn_readlane(dhi_v, s);
                ull d64 = ((ull)dh << 32) | dl;
                if (!((removed >> s) & 1ULL)) removed |= d64;
            }
            // dense parallel apply
            ull acc = 0;
            #pragma unroll
            for (int k = 0; k < 16; ++k) {
                int r = q + 4 * k;
                if (!((removed >> r) & 1ULL)) acc |= crow[k];
            }
            supp |= acc;
        }
        __syncthreads();
    }
    if (tid < 64) {
        supp |= __shfl_xor(supp, 16);
        supp |= __shfl_xor(supp, 32);
        if (tid < 16) s_keep[tid] = ~supp;
    }
    __syncthreads();
    if (tid < 16) {
        int pre = 0;
        for (int u = 0; u < tid; ++u) pre += __popcll(s_keep[u]);
        ull wv = s_keep[tid];
        int rank = pre;
        while (wv) {
            int bit = __builtin_ctzll(wv);
            if (rank < MAXDET) kept_r[rank] = tid * 64 + bit;
            rank++;
            wv &= wv - 1;
        }
        if (tid == 15) s_kc = rank < MAXDET ? rank : MAXDET;
    }
    __syncthreads();
    int kc = s_kc;
    if (tid < MAXDET && tid < kc) kept_n[tid] = topidx[b * KTOP + kept_r[tid]];
    __syncthreads();
    // ---- output phase (all 1024 threads) ----
    float* det = out;                                        // [16][300][6]
    float* mask_o = out + BATCH * MAXDET * 6;                // [16][300]
    float* lgo = out + BATCH * MAXDET * 6 + BATCH * MAXDET;  // [16][300][80]
    for (int idx = tid; idx < MAXDET * 6; idx += 1024) {
        int s = idx / 6, col = idx % 6;
        float v = 0.f;
        if (s < kc) {
            int o = b * KTOP + kept_r[s];
            if (col < 4) v = boxes[o * 4 + col];
            else if (col == 4) v = topsc[o];
            else v = (float)topcls[o];
        }
        det[b * MAXDET * 6 + idx] = v;
    }
    for (int s = tid; s < MAXDET; s += 1024)
        mask_o[b * MAXDET + s] = (s < kc) ? 1.0f : 0.0f;
    // logits rows are 80 floats = 20 float4 (16B-aligned)
    float4* lgo4 = (float4*)(lgo + (size_t)b * MAXDET * NCLS);
    const float4* lg4 = (const float4*)logits;
    for (int idx = tid; idx < MAXDET * (NCLS / 4); idx += 1024) {
        int s = idx / (NCLS / 4), cc = idx % (NCLS / 4);
        float4 v = make_float4(0.f, 0.f, 0.f, 0.f);
        if (s < kc) v = lg4[((size_t)b * NCAND + kept_n[s]) * (NCLS / 4) + cc];
        lgo4[idx] = v;
    }
}

extern "C" void kernel_launch(void* const* d_in, const int* in_sizes, int n_in,
                              void* d_out, int out_size, void* d_ws, size_t ws_size,
                              hipStream_t stream) {
    (void)in_sizes; (void)n_in; (void)out_size; (void)ws_size;
    const float* pred = (const float*)d_in[0];
    const float* logits = (const float*)d_in[1];
    float* out = (float*)d_out;
    char* ws = (char*)d_ws;

    // workspace layout (bytes). score+bx dead after k_topk; M overlays them.
    float* score  = (float*)(ws + 0);                    // 1,612,800
    float* bx     = (float*)(ws + 1612800);              // 6,451,200 (16B aligned)
    int*   cls    = (int*)(ws + 8064000);                // 1,612,800
    ull*   M      = (ull*)(ws + 0);                      // 2,048,000 (overlay on score+bx head)
    int*   hist   = (int*)(ws + 9676800);                // 65,536
    int*   cnt    = (int*)(ws + 9742336);                // 1,024 (16 imgs x 64B)
    int*   topidx = (int*)(ws + 9743360);                // 64,000
    float* topsc  = (float*)(ws + 9807360);              // 64,000
    int*   topcls = (int*)(ws + 9871360);                // 64,000
    float* boxes  = (float*)(ws + 9935360);              // 256,000 (16B aligned)
                                                         // total 10,191,360

    const int nrows = BATCH * NCAND;                     // 403200
    hipMemsetAsync(hist, 0, BATCH * NBINS * sizeof(int), stream);
    k_score<<<nrows / SROWS, 128, 0, stream>>>(pred, score, bx, cls, hist);
    k_topk<<<BATCH, 1024, 0, stream>>>(score, bx, cls, hist, topidx, topsc, topcls, boxes, cnt);
    k_iou<<<(BATCH * KTOP * 16) / 256, 256, 0, stream>>>(boxes, M);
    k_nms_out<<<BATCH, 1024, 0, stream>>>(M, cnt, logits, topidx, topsc, topcls, boxes, out);
}

// Round 12
// 124.034 us; speedup vs baseline: 3.4416x; 1.1153x over previous
//
#include <hip/hip_runtime.h>
#include <hip/hip_bf16.h>

#define BATCH 16
#define NCAND 25200
#define NCLS 80
#define PREDC 85
#define KTOP 1000
#define MAXDET 300
#define CAP 2048
#define NBINS 1024
#define TILE_ROWS 128
#define CONF 0.45f
#define HSCALE ((float)NBINS / (1.0f - 0.45f))
#define CNT_STRIDE 16   // ints; 64B between per-image counters

typedef unsigned long long ull;

// ------- K1: score + argmax class + xyxy box (single pred pass, no atomics) -------
__global__ __launch_bounds__(256) void k_score(const float* __restrict__ pred,
                                               float* __restrict__ score,
                                               float* __restrict__ bx,
                                               int* __restrict__ cls) {
    __shared__ float lds[TILE_ROWS * PREDC];   // 43,520 B
    int tile = blockIdx.x;
    int tid = threadIdx.x;
    size_t base = (size_t)tile * (TILE_ROWS * PREDC);
    const float4* src4 = (const float4*)(pred + base);
    float4* l4 = (float4*)lds;
    const int NV4 = TILE_ROWS * PREDC / 4;  // 2720
    for (int k = tid; k < NV4; k += 256) l4[k] = src4[k];
    __syncthreads();
    if (tid < TILE_ROWS) {
        const float* row = lds + tid * PREDC;
        float obj = row[4];
        float best = -1.0f; int bj = 0;
        #pragma unroll 8
        for (int c = 0; c < NCLS; ++c) {
            float v = row[5 + c] * obj;
            if (v > best) { best = v; bj = c; }   // first-max tie-break (jnp.argmax)
        }
        bool valid = (obj > CONF) && (best > CONF);
        float s = valid ? best : -1.0f;
        int grow = tile * TILE_ROWS + tid;
        score[grow] = s;
        cls[grow] = bj;
        float cx = row[0], cy = row[1], w = row[2], h = row[3];
        ((float4*)bx)[grow] = make_float4(cx - w * 0.5f, cy - h * 0.5f,
                                          cx + w * 0.5f, cy + h * 0.5f);
    }
}

// ---- K2: per-image hist+T+gather+hybrid-bitonic-sort+emit (one 1024-thr block) ----
__device__ __forceinline__ void cmpx(ull& r, ull p, bool keepMin) {
    ull mn = r < p ? r : p;
    ull mx = r < p ? p : r;
    r = keepMin ? mn : mx;
}

__global__ __launch_bounds__(1024) void k_topk(const float* __restrict__ score,
                                               const float* __restrict__ bx,
                                               const int* __restrict__ cls,
                                               int* __restrict__ topidx,
                                               float* __restrict__ topsc,
                                               int* __restrict__ topcls,
                                               float* __restrict__ boxes,
                                               int* __restrict__ cnt) {
    __shared__ int hist[NBINS];        // 4 KB
    __shared__ ull sbuf[CAP];          // 16 KB
    __shared__ int s_T, s_base;
    int b = blockIdx.x, tid = threadIdx.x;
    int lane = tid & 63;
    const float* sc = score + (size_t)b * NCAND;
    const float4* sc4 = (const float4*)sc;
    const int NF4 = NCAND / 4;         // 6300
    hist[tid] = 0;
    if (tid == 0) { s_T = 0; s_base = 0; }
    __syncthreads();
    // pass 1: histogram (float4)
    for (int f = tid; f < NF4; f += 1024) {
        float4 v4 = sc4[f];
        float vs[4] = {v4.x, v4.y, v4.z, v4.w};
        #pragma unroll
        for (int e = 0; e < 4; ++e) {
            float s = vs[e];
            if (s > CONF) {
                int bin = (int)((s - CONF) * HSCALE);
                bin = bin < 0 ? 0 : (bin > NBINS - 1 ? NBINS - 1 : bin);
                atomicAdd(&hist[bin], 1);
            }
        }
    }
    __syncthreads();
    // suffix scan (Hillis-Steele, 1 bin/thread)
    for (int off = 1; off < NBINS; off <<= 1) {
        int v = (tid + off < NBINS) ? hist[tid + off] : 0;
        __syncthreads();
        hist[tid] += v;
        __syncthreads();
    }
    {
        int S = hist[tid];
        int Sn = (tid + 1 < NBINS) ? hist[tid + 1] : 0;
        if (S >= KTOP && Sn < KTOP) s_T = tid;   // unique (suffix monotone)
    }
    sbuf[tid] = ~0ULL;
    sbuf[tid + 1024] = ~0ULL;
    __syncthreads();
    int T = s_T;
    // pass 2: gather survivors into LDS (wave-compaction, LDS-atomic base)
    for (int f = tid; f < NF4; f += 1024) {
        float4 v4 = sc4[f];
        float vs[4] = {v4.x, v4.y, v4.z, v4.w};
        #pragma unroll
        for (int e = 0; e < 4; ++e) {
            float s = vs[e];
            bool want = false;
            if (s > CONF) {
                int bin = (int)((s - CONF) * HSCALE);
                bin = bin < 0 ? 0 : (bin > NBINS - 1 ? NBINS - 1 : bin);
                want = (bin >= T);
            }
            ull m = __ballot(want);
            int wb = 0;
            if (lane == 0 && m) wb = atomicAdd(&s_base, (int)__popcll(m));
            wb = __shfl(wb, 0);
            if (want) {
                int pos = wb + (int)__popcll(m & ((1ULL << lane) - 1ULL));
                if (pos < CAP) {
                    unsigned sb2 = __float_as_uint(s);
                    sbuf[pos] = ((ull)(~sb2) << 32) | (unsigned)(f * 4 + e);
                }
            }
        }
    }
    __syncthreads();
    int C2 = s_base; if (C2 > CAP) C2 = CAP;
    ull key0;   // rank-tid key after sort
    if (C2 <= 1024) {
        // ---- fast path: sort 1024 keys, 1 reg/thread ----
        ull r0 = sbuf[tid];
        #pragma unroll
        for (unsigned k = 2; k <= 64; k <<= 1) {
            #pragma unroll
            for (unsigned j = k >> 1; j > 0; j >>= 1) {
                ull p0 = __shfl_xor(r0, (int)j);
                bool amLow = ((tid & j) == 0);
                cmpx(r0, p0, amLow == ((tid & k) == 0));
            }
        }
        #pragma unroll
        for (unsigned k = 128; k <= 512; k <<= 1) {
            #pragma unroll
            for (unsigned j = k >> 1; j >= 64; j >>= 1) {
                sbuf[tid] = r0;
                __syncthreads();
                ull p0 = sbuf[tid ^ j];
                cmpx(r0, p0, ((tid & j) == 0) == ((tid & k) == 0));
                __syncthreads();
            }
            #pragma unroll
            for (unsigned j = 32; j > 0; j >>= 1) {
                ull p0 = __shfl_xor(r0, (int)j);
                bool amLow = ((tid & j) == 0);
                cmpx(r0, p0, amLow == ((tid & k) == 0));
            }
        }
        // k = 1024 final ascending merge
        #pragma unroll
        for (unsigned j = 512; j >= 64; j >>= 1) {
            sbuf[tid] = r0;
            __syncthreads();
            ull p0 = sbuf[tid ^ j];
            cmpx(r0, p0, ((tid & j) == 0));
            __syncthreads();
        }
        #pragma unroll
        for (unsigned j = 32; j > 0; j >>= 1) {
            ull p0 = __shfl_xor(r0, (int)j);
            cmpx(r0, p0, ((tid & j) == 0));
        }
        key0 = r0;
    } else {
        // ---- full path: sort 2048 keys, 2 regs/thread ----
        ull r0 = sbuf[tid];
        ull r1 = sbuf[tid + 1024];
        int t2 = tid + 1024;
        #pragma unroll
        for (unsigned k = 2; k <= 64; k <<= 1) {
            #pragma unroll
            for (unsigned j = k >> 1; j > 0; j >>= 1) {
                ull p0 = __shfl_xor(r0, (int)j);
                ull p1 = __shfl_xor(r1, (int)j);
                bool amLow = ((tid & j) == 0);
                cmpx(r0, p0, amLow == ((tid & k) == 0));
                cmpx(r1, p1, amLow == ((t2 & k) == 0));
            }
        }
        #pragma unroll
        for (unsigned k = 128; k <= 1024; k <<= 1) {
            #pragma unroll
            for (unsigned j = k >> 1; j >= 64; j >>= 1) {
                sbuf[tid] = r0; sbuf[t2] = r1;
                __syncthreads();
                ull p0 = sbuf[tid ^ j];
                ull p1 = sbuf[t2 ^ j];
                cmpx(r0, p0, ((tid & j) == 0) == ((tid & k) == 0));
                cmpx(r1, p1, ((t2 & j) == 0) == ((t2 & k) == 0));
                __syncthreads();
            }
            #pragma unroll
            for (unsigned j = 32; j > 0; j >>= 1) {
                ull p0 = __shfl_xor(r0, (int)j);
                ull p1 = __shfl_xor(r1, (int)j);
                bool amLow = ((tid & j) == 0);
                cmpx(r0, p0, amLow == ((tid & k) == 0));
                cmpx(r1, p1, amLow == ((t2 & k) == 0));
            }
        }
        {
            if (r1 < r0) { ull t = r0; r0 = r1; r1 = t; }   // k=2048, j=1024 in-thread
            #pragma unroll
            for (unsigned j = 512; j >= 64; j >>= 1) {
                sbuf[tid] = r0; sbuf[t2] = r1;
                __syncthreads();
                ull p0 = sbuf[tid ^ j];
                ull p1 = sbuf[t2 ^ j];
                cmpx(r0, p0, ((tid & j) == 0));
                cmpx(r1, p1, ((t2 & j) == 0));
                __syncthreads();
            }
            #pragma unroll
            for (unsigned j = 32; j > 0; j >>= 1) {
                ull p0 = __shfl_xor(r0, (int)j);
                ull p1 = __shfl_xor(r1, (int)j);
                bool amLow = ((tid & j) == 0);
                cmpx(r0, p0, amLow);
                cmpx(r1, p1, amLow);
            }
        }
        key0 = r0;
    }
    // emit top-K from key0 (ranks 0..1023)
    if (tid < KTOP) {
        int o = b * KTOP + tid;
        if (tid < C2) {
            int n = (int)(key0 & 0xFFFFFFFFULL);
            float s = __uint_as_float(~(unsigned)(key0 >> 32));
            topidx[o] = n;
            topsc[o] = s;
            topcls[o] = cls[b * NCAND + n];
            ((float4*)boxes)[o] = ((const float4*)bx)[b * NCAND + n];
        } else {
            topidx[o] = 0; topsc[o] = -1.0f; topcls[o] = 0;
            ((float4*)boxes)[o] = make_float4(0.f, 0.f, 0.f, 0.f);
        }
    }
    if (tid == 0) cnt[b * CNT_STRIDE] = C2;
}

// ---------------- K3: IoU bitmask (j>i, iou>thr), full-grid parallel ----------------
__global__ __launch_bounds__(256) void k_iou(const float* __restrict__ boxes,
                                             ull* __restrict__ M) {
    #pragma clang fp contract(off)
    int g = blockIdx.x * 256 + threadIdx.x;   // 16*1000*16 = 256000
    int w = g & 15;
    int bi = g >> 4;                          // 0..15999
    int i = bi % KTOP;
    int b = bi / KTOP;
    int j0 = w * 64;
    if (j0 + 63 <= i) {                       // whole block strictly j<=i -> zero
        M[(size_t)bi * 16 + w] = 0ULL;
        return;
    }
    const float4* bxp = (const float4*)boxes + (size_t)b * KTOP;
    float4 A = bxp[i];
    float areaA = (A.z - A.x) * (A.w - A.y);
    ull word = 0;
    int jend = j0 + 64; if (jend > KTOP) jend = KTOP;
    #pragma unroll 4
    for (int j = j0; j < jend; ++j) {
        float4 Bb = bxp[j];
        float areaB = (Bb.z - Bb.x) * (Bb.w - Bb.y);
        float lx = fmaxf(A.x, Bb.x), ly = fmaxf(A.y, Bb.y);
        float rx = fminf(A.z, Bb.z), ry = fminf(A.w, Bb.w);
        float ww = rx - lx; ww = ww > 0.f ? ww : 0.f;
        float hh = ry - ly; hh = hh > 0.f ? hh : 0.f;
        float inter = ww * hh;
        float denom = ((areaA + areaB) - inter) + 1e-9f;
        float iou = inter / denom;
        if (j > i && iou > 0.45f) word |= 1ULL << (j - j0);
    }
    M[(size_t)bi * 16 + w] = word;
}

// ------ K4: block-NMS (reg-split staged dbuf + wave0 scalar resolve) + outputs ------
__global__ __launch_bounds__(1024) void k_nms_out(const ull* __restrict__ M,
                                                  const int* __restrict__ cnt,
                                                  const float* __restrict__ logits,
                                                  const int* __restrict__ topidx,
                                                  const float* __restrict__ topsc,
                                                  const int* __restrict__ topcls,
                                                  const float* __restrict__ boxes,
                                                  float* __restrict__ out) {
    __shared__ ull buf[2][64 * 17];   // stride-17 pad: <=4-way bank conflict
    __shared__ ull s_keep[16];
    __shared__ int kept_r[MAXDET];
    __shared__ int kept_n[MAXDET];
    __shared__ int s_kc;
    int b = blockIdx.x, tid = threadIdx.x;
    int kc0 = cnt[b * CNT_STRIDE]; if (kc0 > KTOP) kc0 = KTOP;
    const ull* Mb = M + (size_t)b * KTOP * 16;
    // stage block 0 directly (all 1024 threads, coalesced)
    buf[0][(tid >> 4) * 17 + (tid & 15)] = Mb[tid];
    // staging threads: issue block 1 loads into regs (written to LDS at iter 0)
    int st = tid - 64;                 // staging index 0..959
    ull v0 = 0, v1 = 0;
    if (tid >= 64) {
        int g0 = 1024 + st;
        v0 = Mb[g0 < 16000 ? g0 : 15999];
        if (st < 64) {
            int g1 = 1024 + 960 + st;
            v1 = Mb[g1 < 16000 ? g1 : 15999];
        }
    }
    __syncthreads();
    ull supp;
    {
        int w = tid & 15, lo = w * 64;
        if (kc0 <= lo) supp = ~0ULL;
        else if (kc0 >= lo + 64) supp = 0ULL;
        else supp = (~0ULL) << (kc0 - lo);
    }
    for (int rb = 0; rb < 16; ++rb) {
        int cur = rb & 1, nxt = cur ^ 1;
        if (tid >= 64) {
            if (rb < 15) {
                // write block rb+1 from regs (loads issued one iteration ago)
                buf[nxt][(st >> 4) * 17 + (st & 15)] = v0;
                if (st < 64) {
                    int u1 = 960 + st;
                    buf[nxt][(u1 >> 4) * 17 + (u1 & 15)] = v1;
                }
                // issue loads for block rb+2
                if (rb + 2 < 16) {
                    int g0 = (rb + 2) * 1024 + st;
                    v0 = Mb[g0 < 16000 ? g0 : 15999];
                    if (st < 64) {
                        int g1 = (rb + 2) * 1024 + 960 + st;
                        v1 = Mb[g1 < 16000 ? g1 : 15999];
                    }
                }
            }
        } else {
            int l = tid, w = l & 15, q = l >> 4;
            const ull* B = buf[cur];
            ull drow = B[l * 17 + rb];
            ull crow[16];
            #pragma unroll
            for (int k = 0; k < 16; ++k) crow[k] = B[(q + 4 * k) * 17 + w];
            // merged supp word rb -> wave-uniform scalar
            int slo = (int)(supp & 0xffffffffULL);
            int shi = (int)(supp >> 32);
            unsigned rlo = (unsigned)__builtin_amdgcn_readlane(slo, rb)
                         | (unsigned)__builtin_amdgcn_readlane(slo, rb + 16)
                         | (unsigned)__builtin_amdgcn_readlane(slo, rb + 32)
                         | (unsigned)__builtin_amdgcn_readlane(slo, rb + 48);
            unsigned rhi = (unsigned)__builtin_amdgcn_readlane(shi, rb)
                         | (unsigned)__builtin_amdgcn_readlane(shi, rb + 16)
                         | (unsigned)__builtin_amdgcn_readlane(shi, rb + 32)
                         | (unsigned)__builtin_amdgcn_readlane(shi, rb + 48);
            ull removed = ((ull)rhi << 32) | rlo;
            int dlo_v = (int)(drow & 0xffffffffULL);
            int dhi_v = (int)(drow >> 32);
            // 64-step serial resolve on wave-uniform scalars (SALU chain)
            #pragma unroll
            for (int s = 0; s < 64; ++s) {
                unsigned dl = (unsigned)__builtin_amdgcn_readlane(dlo_v, s);
                unsigned dh = (unsigned)__builtin_amdgcn_readlane(dhi_v, s);
                ull d64 = ((ull)dh << 32) | dl;
                if (!((removed >> s) & 1ULL)) removed |= d64;
            }
            // dense parallel apply
            ull acc = 0;
            #pragma unroll
            for (int k = 0; k < 16; ++k) {
                int r = q + 4 * k;
                if (!((removed >> r) & 1ULL)) acc |= crow[k];
            }
            supp |= acc;
        }
        __syncthreads();
    }
    if (tid < 64) {
        supp |= __shfl_xor(supp, 16);
        supp |= __shfl_xor(supp, 32);
        if (tid < 16) s_keep[tid] = ~supp;
    }
    __syncthreads();
    if (tid < 16) {
        int pre = 0;
        for (int u = 0; u < tid; ++u) pre += __popcll(s_keep[u]);
        ull wv = s_keep[tid];
        int rank = pre;
        while (wv) {
            int bit = __builtin_ctzll(wv);
            if (rank < MAXDET) kept_r[rank] = tid * 64 + bit;
            rank++;
            wv &= wv - 1;
        }
        if (tid == 15) s_kc = rank < MAXDET ? rank : MAXDET;
    }
    __syncthreads();
    int kc = s_kc;
    if (tid < MAXDET && tid < kc) kept_n[tid] = topidx[b * KTOP + kept_r[tid]];
    __syncthreads();
    // ---- output phase (all 1024 threads) ----
    float* det = out;                                        // [16][300][6]
    float* mask_o = out + BATCH * MAXDET * 6;                // [16][300]
    float* lgo = out + BATCH * MAXDET * 6 + BATCH * MAXDET;  // [16][300][80]
    for (int idx = tid; idx < MAXDET * 6; idx += 1024) {
        int s = idx / 6, col = idx % 6;
        float v = 0.f;
        if (s < kc) {
            int o = b * KTOP + kept_r[s];
            if (col < 4) v = boxes[o * 4 + col];
            else if (col == 4) v = topsc[o];
            else v = (float)topcls[o];
        }
        det[b * MAXDET * 6 + idx] = v;
    }
    for (int s = tid; s < MAXDET; s += 1024)
        mask_o[b * MAXDET + s] = (s < kc) ? 1.0f : 0.0f;
    // logits rows are 80 floats = 20 float4 (16B-aligned)
    float4* lgo4 = (float4*)(lgo + (size_t)b * MAXDET * NCLS);
    const float4* lg4 = (const float4*)logits;
    for (int idx = tid; idx < MAXDET * (NCLS / 4); idx += 1024) {
        int s = idx / (NCLS / 4), cc = idx % (NCLS / 4);
        float4 v = make_float4(0.f, 0.f, 0.f, 0.f);
        if (s < kc) v = lg4[((size_t)b * NCAND + kept_n[s]) * (NCLS / 4) + cc];
        lgo4[idx] = v;
    }
}

extern "C" void kernel_launch(void* const* d_in, const int* in_sizes, int n_in,
                              void* d_out, int out_size, void* d_ws, size_t ws_size,
                              hipStream_t stream) {
    (void)in_sizes; (void)n_in; (void)out_size; (void)ws_size;
    const float* pred = (const float*)d_in[0];
    const float* logits = (const float*)d_in[1];
    float* out = (float*)d_out;
    char* ws = (char*)d_ws;

    // workspace layout (bytes). score+bx dead after k_topk; M overlays them.
    float* score  = (float*)(ws + 0);                    // 1,612,800
    float* bx     = (float*)(ws + 1612800);              // 6,451,200 (16B aligned)
    int*   cls    = (int*)(ws + 8064000);                // 1,612,800
    ull*   M      = (ull*)(ws + 0);                      // 2,048,000 (overlay on score+bx head)
    int*   cnt    = (int*)(ws + 9676800);                // 1,024 (16 imgs x 64B)
    int*   topidx = (int*)(ws + 9677824);                // 64,000
    float* topsc  = (float*)(ws + 9741824);              // 64,000
    int*   topcls = (int*)(ws + 9805824);                // 64,000
    float* boxes  = (float*)(ws + 9869824);              // 256,000 (16B aligned)
                                                         // total 10,125,824

    const int nrows = BATCH * NCAND;                     // 403200
    k_score<<<nrows / TILE_ROWS, 256, 0, stream>>>(pred, score, bx, cls);
    k_topk<<<BATCH, 1024, 0, stream>>>(score, bx, cls, topidx, topsc, topcls, boxes, cnt);
    k_iou<<<(BATCH * KTOP * 16) / 256, 256, 0, stream>>>(boxes, M);
    k_nms_out<<<BATCH, 1024, 0, stream>>>(M, cnt, logits, topidx, topsc, topcls, boxes, out);
}

// Round 13
// 122.865 us; speedup vs baseline: 3.4743x; 1.0095x over previous
//
#include <hip/hip_runtime.h>
#include <hip/hip_bf16.h>

#define BATCH 16
#define NCAND 25200
#define NCLS 80
#define PREDC 85
#define KTOP 1000
#define MAXDET 300
#define CAP 2048
#define NBINS 1024
#define TILE_ROWS 128
#define CONF 0.45f
#define HSCALE ((float)NBINS / (1.0f - 0.45f))
#define CNT_STRIDE 16   // ints; 64B between per-image counters

typedef unsigned long long ull;

// ------- K1: score + argmax class + xyxy box (single pred pass, no atomics) -------
__global__ __launch_bounds__(256) void k_score(const float* __restrict__ pred,
                                               float* __restrict__ score,
                                               float* __restrict__ bx,
                                               int* __restrict__ cls) {
    __shared__ float lds[TILE_ROWS * PREDC];   // 43,520 B
    int tile = blockIdx.x;
    int tid = threadIdx.x;
    size_t base = (size_t)tile * (TILE_ROWS * PREDC);
    const float4* src4 = (const float4*)(pred + base);
    float4* l4 = (float4*)lds;
    const int NV4 = TILE_ROWS * PREDC / 4;  // 2720
    for (int k = tid; k < NV4; k += 256) l4[k] = src4[k];
    __syncthreads();
    if (tid < TILE_ROWS) {
        const float* row = lds + tid * PREDC;
        float obj = row[4];
        float best = -1.0f; int bj = 0;
        #pragma unroll 8
        for (int c = 0; c < NCLS; ++c) {
            float v = row[5 + c] * obj;
            if (v > best) { best = v; bj = c; }   // first-max tie-break (jnp.argmax)
        }
        bool valid = (obj > CONF) && (best > CONF);
        float s = valid ? best : -1.0f;
        int grow = tile * TILE_ROWS + tid;
        score[grow] = s;
        cls[grow] = bj;
        float cx = row[0], cy = row[1], w = row[2], h = row[3];
        ((float4*)bx)[grow] = make_float4(cx - w * 0.5f, cy - h * 0.5f,
                                          cx + w * 0.5f, cy + h * 0.5f);
    }
}

// ---- K2: per-image hist+T+gather+hybrid-bitonic-sort+emit (one 1024-thr block) ----
__device__ __forceinline__ void cmpx(ull& r, ull p, bool keepMin) {
    ull mn = r < p ? r : p;
    ull mx = r < p ? p : r;
    r = keepMin ? mn : mx;
}

__global__ __launch_bounds__(1024) void k_topk(const float* __restrict__ score,
                                               const float* __restrict__ bx,
                                               const int* __restrict__ cls,
                                               int* __restrict__ topidx,
                                               float* __restrict__ topsc,
                                               int* __restrict__ topcls,
                                               float* __restrict__ boxes,
                                               int* __restrict__ cnt) {
    __shared__ int hist[NBINS];        // 4 KB
    __shared__ ull sbuf[2][CAP];       // 32 KB (ping-pong sort buffers)
    __shared__ int s_T, s_base;
    int b = blockIdx.x, tid = threadIdx.x;
    int lane = tid & 63;
    const float* sc = score + (size_t)b * NCAND;
    const float4* sc4 = (const float4*)sc;
    const int NF4 = NCAND / 4;         // 6300
    hist[tid] = 0;
    if (tid == 0) { s_T = 0; s_base = 0; }
    __syncthreads();
    // pass 1: histogram (float4)
    for (int f = tid; f < NF4; f += 1024) {
        float4 v4 = sc4[f];
        float vs[4] = {v4.x, v4.y, v4.z, v4.w};
        #pragma unroll
        for (int e = 0; e < 4; ++e) {
            float s = vs[e];
            if (s > CONF) {
                int bin = (int)((s - CONF) * HSCALE);
                bin = bin < 0 ? 0 : (bin > NBINS - 1 ? NBINS - 1 : bin);
                atomicAdd(&hist[bin], 1);
            }
        }
    }
    __syncthreads();
    // wave 0: single-wave shfl suffix scan + threshold bin T (no barriers);
    // waves 1..15: sentinel-fill sbuf[0] concurrently.
    if (tid < 64) {
        int l = tid;
        int h[16];
        #pragma unroll
        for (int i = 0; i < 16; ++i) h[i] = hist[l * 16 + i];
        #pragma unroll
        for (int i = 14; i >= 0; --i) h[i] += h[i + 1];   // in-lane suffix sums
        int tot = h[0];
        int suf = tot;                                     // inclusive cross-lane suffix
        #pragma unroll
        for (int off = 1; off < 64; off <<= 1) {
            int src = (l + off < 64) ? l + off : l;
            int v = __shfl(suf, src);
            suf += (l + off < 64) ? v : 0;
        }
        int srcn = (l + 1 < 64) ? l + 1 : l;
        int Snext0 = __shfl(suf, srcn);                    // S((l+1)*16)
        Snext0 = (l + 1 < 64) ? Snext0 : 0;
        int excl = suf - tot;                              // sum over lanes > l
        #pragma unroll
        for (int i = 0; i < 16; ++i) {
            int S = excl + h[i];
            int Sn = (i < 15) ? (excl + h[i + 1]) : Snext0;
            if (S >= KTOP && Sn < KTOP) s_T = l * 16 + i;  // unique (suffix monotone)
        }
    } else {
        for (int u = tid - 64; u < CAP; u += 960) sbuf[0][u] = ~0ULL;
    }
    __syncthreads();
    int T = s_T;
    // pass 2: gather survivors into LDS (wave-compaction, LDS-atomic base)
    for (int f = tid; f < NF4; f += 1024) {
        float4 v4 = sc4[f];
        float vs[4] = {v4.x, v4.y, v4.z, v4.w};
        #pragma unroll
        for (int e = 0; e < 4; ++e) {
            float s = vs[e];
            bool want = false;
            if (s > CONF) {
                int bin = (int)((s - CONF) * HSCALE);
                bin = bin < 0 ? 0 : (bin > NBINS - 1 ? NBINS - 1 : bin);
                want = (bin >= T);
            }
            ull m = __ballot(want);
            int wb = 0;
            if (lane == 0 && m) wb = atomicAdd(&s_base, (int)__popcll(m));
            wb = __shfl(wb, 0);
            if (want) {
                int pos = wb + (int)__popcll(m & ((1ULL << lane) - 1ULL));
                if (pos < CAP) {
                    unsigned sb2 = __float_as_uint(s);
                    sbuf[0][pos] = ((ull)(~sb2) << 32) | (unsigned)(f * 4 + e);
                }
            }
        }
    }
    __syncthreads();
    int C2 = s_base; if (C2 > CAP) C2 = CAP;
    ull key0;   // rank-tid key after sort
    if (C2 <= 1024) {
        // ---- fast path: sort 1024 keys, 1 reg/thread, ping-pong LDS rounds ----
        ull r0 = sbuf[0][tid];
        int p = 0;
        #pragma unroll
        for (unsigned k = 2; k <= 64; k <<= 1) {
            #pragma unroll
            for (unsigned j = k >> 1; j > 0; j >>= 1) {
                ull p0 = __shfl_xor(r0, (int)j);
                bool amLow = ((tid & j) == 0);
                cmpx(r0, p0, amLow == ((tid & k) == 0));
            }
        }
        #pragma unroll
        for (unsigned k = 128; k <= 512; k <<= 1) {
            #pragma unroll
            for (unsigned j = k >> 1; j >= 64; j >>= 1) {
                ull* nb = &sbuf[p ^ 1][0];
                nb[tid] = r0;
                __syncthreads();
                ull p0 = nb[tid ^ j];
                cmpx(r0, p0, ((tid & j) == 0) == ((tid & k) == 0));
                p ^= 1;
            }
            #pragma unroll
            for (unsigned j = 32; j > 0; j >>= 1) {
                ull p0 = __shfl_xor(r0, (int)j);
                bool amLow = ((tid & j) == 0);
                cmpx(r0, p0, amLow == ((tid & k) == 0));
            }
        }
        // k = 1024 final ascending merge
        #pragma unroll
        for (unsigned j = 512; j >= 64; j >>= 1) {
            ull* nb = &sbuf[p ^ 1][0];
            nb[tid] = r0;
            __syncthreads();
            ull p0 = nb[tid ^ j];
            cmpx(r0, p0, ((tid & j) == 0));
            p ^= 1;
        }
        #pragma unroll
        for (unsigned j = 32; j > 0; j >>= 1) {
            ull p0 = __shfl_xor(r0, (int)j);
            cmpx(r0, p0, ((tid & j) == 0));
        }
        key0 = r0;
    } else {
        // ---- full path: sort 2048 keys, 2 regs/thread, ping-pong LDS rounds ----
        ull r0 = sbuf[0][tid];
        ull r1 = sbuf[0][tid + 1024];
        int t2 = tid + 1024;
        int p = 0;
        #pragma unroll
        for (unsigned k = 2; k <= 64; k <<= 1) {
            #pragma unroll
            for (unsigned j = k >> 1; j > 0; j >>= 1) {
                ull p0 = __shfl_xor(r0, (int)j);
                ull p1 = __shfl_xor(r1, (int)j);
                bool amLow = ((tid & j) == 0);
                cmpx(r0, p0, amLow == ((tid & k) == 0));
                cmpx(r1, p1, amLow == ((t2 & k) == 0));
            }
        }
        #pragma unroll
        for (unsigned k = 128; k <= 1024; k <<= 1) {
            #pragma unroll
            for (unsigned j = k >> 1; j >= 64; j >>= 1) {
                ull* nb = &sbuf[p ^ 1][0];
                nb[tid] = r0; nb[t2] = r1;
                __syncthreads();
                ull p0 = nb[tid ^ j];
                ull p1 = nb[t2 ^ j];
                cmpx(r0, p0, ((tid & j) == 0) == ((tid & k) == 0));
                cmpx(r1, p1, ((t2 & j) == 0) == ((t2 & k) == 0));
                p ^= 1;
            }
            #pragma unroll
            for (unsigned j = 32; j > 0; j >>= 1) {
                ull p0 = __shfl_xor(r0, (int)j);
                ull p1 = __shfl_xor(r1, (int)j);
                bool amLow = ((tid & j) == 0);
                cmpx(r0, p0, amLow == ((tid & k) == 0));
                cmpx(r1, p1, amLow == ((t2 & k) == 0));
            }
        }
        {
            if (r1 < r0) { ull t = r0; r0 = r1; r1 = t; }   // k=2048, j=1024 in-thread
            #pragma unroll
            for (unsigned j = 512; j >= 64; j >>= 1) {
                ull* nb = &sbuf[p ^ 1][0];
                nb[tid] = r0; nb[t2] = r1;
                __syncthreads();
                ull p0 = nb[tid ^ j];
                ull p1 = nb[t2 ^ j];
                cmpx(r0, p0, ((tid & j) == 0));
                cmpx(r1, p1, ((t2 & j) == 0));
                p ^= 1;
            }
            #pragma unroll
            for (unsigned j = 32; j > 0; j >>= 1) {
                ull p0 = __shfl_xor(r0, (int)j);
                ull p1 = __shfl_xor(r1, (int)j);
                bool amLow = ((tid & j) == 0);
                cmpx(r0, p0, amLow);
                cmpx(r1, p1, amLow);
            }
        }
        key0 = r0;
    }
    // emit top-K from key0 (ranks 0..1023)
    if (tid < KTOP) {
        int o = b * KTOP + tid;
        if (tid < C2) {
            int n = (int)(key0 & 0xFFFFFFFFULL);
            float s = __uint_as_float(~(unsigned)(key0 >> 32));
            topidx[o] = n;
            topsc[o] = s;
            topcls[o] = cls[b * NCAND + n];
            ((float4*)boxes)[o] = ((const float4*)bx)[b * NCAND + n];
        } else {
            topidx[o] = 0; topsc[o] = -1.0f; topcls[o] = 0;
            ((float4*)boxes)[o] = make_float4(0.f, 0.f, 0.f, 0.f);
        }
    }
    if (tid == 0) cnt[b * CNT_STRIDE] = C2;
}

// ---------------- K3: IoU bitmask (j>i, iou>thr), full-grid parallel ----------------
__global__ __launch_bounds__(256) void k_iou(const float* __restrict__ boxes,
                                             ull* __restrict__ M) {
    #pragma clang fp contract(off)
    int g = blockIdx.x * 256 + threadIdx.x;   // 16*1000*16 = 256000
    int w = g & 15;
    int bi = g >> 4;                          // 0..15999
    int i = bi % KTOP;
    int b = bi / KTOP;
    int j0 = w * 64;
    if (j0 + 63 <= i) {                       // whole block strictly j<=i -> zero
        M[(size_t)bi * 16 + w] = 0ULL;
        return;
    }
    const float4* bxp = (const float4*)boxes + (size_t)b * KTOP;
    float4 A = bxp[i];
    float areaA = (A.z - A.x) * (A.w - A.y);
    ull word = 0;
    int jend = j0 + 64; if (jend > KTOP) jend = KTOP;
    #pragma unroll 4
    for (int j = j0; j < jend; ++j) {
        float4 Bb = bxp[j];
        float areaB = (Bb.z - Bb.x) * (Bb.w - Bb.y);
        float lx = fmaxf(A.x, Bb.x), ly = fmaxf(A.y, Bb.y);
        float rx = fminf(A.z, Bb.z), ry = fminf(A.w, Bb.w);
        float ww = rx - lx; ww = ww > 0.f ? ww : 0.f;
        float hh = ry - ly; hh = hh > 0.f ? hh : 0.f;
        float inter = ww * hh;
        float denom = ((areaA + areaB) - inter) + 1e-9f;
        float iou = inter / denom;
        if (j > i && iou > 0.45f) word |= 1ULL << (j - j0);
    }
    M[(size_t)bi * 16 + w] = word;
}

// ------ K4: block-NMS (reg-split staged dbuf + wave0 scalar resolve) + outputs ------
__global__ __launch_bounds__(1024) void k_nms_out(const ull* __restrict__ M,
                                                  const int* __restrict__ cnt,
                                                  const float* __restrict__ logits,
                                                  const int* __restrict__ topidx,
                                                  const float* __restrict__ topsc,
                                                  const int* __restrict__ topcls,
                                                  const float* __restrict__ boxes,
                                                  float* __restrict__ out) {
    __shared__ ull buf[2][64 * 17];   // stride-17 pad: <=4-way bank conflict
    __shared__ ull s_keep[16];
    __shared__ int kept_r[MAXDET];
    __shared__ int kept_n[MAXDET];
    __shared__ int s_kc;
    int b = blockIdx.x, tid = threadIdx.x;
    int kc0 = cnt[b * CNT_STRIDE]; if (kc0 > KTOP) kc0 = KTOP;
    const ull* Mb = M + (size_t)b * KTOP * 16;
    // stage block 0 directly (all 1024 threads, coalesced)
    buf[0][(tid >> 4) * 17 + (tid & 15)] = Mb[tid];
    // staging threads: issue block 1 loads into regs (written to LDS at iter 0)
    int st = tid - 64;                 // staging index 0..959
    ull v0 = 0, v1 = 0;
    if (tid >= 64) {
        int g0 = 1024 + st;
        v0 = Mb[g0 < 16000 ? g0 : 15999];
        if (st < 64) {
            int g1 = 1024 + 960 + st;
            v1 = Mb[g1 < 16000 ? g1 : 15999];
        }
    }
    __syncthreads();
    ull supp;
    {
        int w = tid & 15, lo = w * 64;
        if (kc0 <= lo) supp = ~0ULL;
        else if (kc0 >= lo + 64) supp = 0ULL;
        else supp = (~0ULL) << (kc0 - lo);
    }
    for (int rb = 0; rb < 16; ++rb) {
        int cur = rb & 1, nxt = cur ^ 1;
        if (tid >= 64) {
            if (rb < 15) {
                // write block rb+1 from regs (loads issued one iteration ago)
                buf[nxt][(st >> 4) * 17 + (st & 15)] = v0;
                if (st < 64) {
                    int u1 = 960 + st;
                    buf[nxt][(u1 >> 4) * 17 + (u1 & 15)] = v1;
                }
                // issue loads for block rb+2
                if (rb + 2 < 16) {
                    int g0 = (rb + 2) * 1024 + st;
                    v0 = Mb[g0 < 16000 ? g0 : 15999];
                    if (st < 64) {
                        int g1 = (rb + 2) * 1024 + 960 + st;
                        v1 = Mb[g1 < 16000 ? g1 : 15999];
                    }
                }
            }
        } else {
            int l = tid, w = l & 15, q = l >> 4;
            const ull* B = buf[cur];
            ull drow = B[l * 17 + rb];
            ull crow[16];
            #pragma unroll
            for (int k = 0; k < 16; ++k) crow[k] = B[(q + 4 * k) * 17 + w];
            // merged supp word rb -> wave-uniform scalar
            int slo = (int)(supp & 0xffffffffULL);
            int shi = (int)(supp >> 32);
            unsigned rlo = (unsigned)__builtin_amdgcn_readlane(slo, rb)
                         | (unsigned)__builtin_amdgcn_readlane(slo, rb + 16)
                         | (unsigned)__builtin_amdgcn_readlane(slo, rb + 32)
                         | (unsigned)__builtin_amdgcn_readlane(slo, rb + 48);
            unsigned rhi = (unsigned)__builtin_amdgcn_readlane(shi, rb)
                         | (unsigned)__builtin_amdgcn_readlane(shi, rb + 16)
                         | (unsigned)__builtin_amdgcn_readlane(shi, rb + 32)
                         | (unsigned)__builtin_amdgcn_readlane(shi, rb + 48);
            ull removed = ((ull)rhi << 32) | rlo;
            int dlo_v = (int)(drow & 0xffffffffULL);
            int dhi_v = (int)(drow >> 32);
            // 64-step serial resolve on wave-uniform scalars (SALU chain)
            #pragma unroll
            for (int s = 0; s < 64; ++s) {
                unsigned dl = (unsigned)__builtin_amdgcn_readlane(dlo_v, s);
                unsigned dh = (unsigned)__builtin_amdgcn_readlane(dhi_v, s);
                ull d64 = ((ull)dh << 32) | dl;
                if (!((removed >> s) & 1ULL)) removed |= d64;
            }
            // dense parallel apply
            ull acc = 0;
            #pragma unroll
            for (int k = 0; k < 16; ++k) {
                int r = q + 4 * k;
                if (!((removed >> r) & 1ULL)) acc |= crow[k];
            }
            supp |= acc;
        }
        __syncthreads();
    }
    if (tid < 64) {
        supp |= __shfl_xor(supp, 16);
        supp |= __shfl_xor(supp, 32);
        if (tid < 16) s_keep[tid] = ~supp;
    }
    __syncthreads();
    if (tid < 16) {
        int pre = 0;
        for (int u = 0; u < tid; ++u) pre += __popcll(s_keep[u]);
        ull wv = s_keep[tid];
        int rank = pre;
        while (wv) {
            int bit = __builtin_ctzll(wv);
            if (rank < MAXDET) kept_r[rank] = tid * 64 + bit;
            rank++;
            wv &= wv - 1;
        }
        if (tid == 15) s_kc = rank < MAXDET ? rank : MAXDET;
    }
    __syncthreads();
    int kc = s_kc;
    if (tid < MAXDET && tid < kc) kept_n[tid] = topidx[b * KTOP + kept_r[tid]];
    __syncthreads();
    // ---- output phase (all 1024 threads) ----
    float* det = out;                                        // [16][300][6]
    float* mask_o = out + BATCH * MAXDET * 6;                // [16][300]
    float* lgo = out + BATCH * MAXDET * 6 + BATCH * MAXDET;  // [16][300][80]
    for (int idx = tid; idx < MAXDET * 6; idx += 1024) {
        int s = idx / 6, col = idx % 6;
        float v = 0.f;
        if (s < kc) {
            int o = b * KTOP + kept_r[s];
            if (col < 4) v = boxes[o * 4 + col];
            else if (col == 4) v = topsc[o];
            else v = (float)topcls[o];
        }
        det[b * MAXDET * 6 + idx] = v;
    }
    for (int s = tid; s < MAXDET; s += 1024)
        mask_o[b * MAXDET + s] = (s < kc) ? 1.0f : 0.0f;
    // logits rows are 80 floats = 20 float4 (16B-aligned)
    float4* lgo4 = (float4*)(lgo + (size_t)b * MAXDET * NCLS);
    const float4* lg4 = (const float4*)logits;
    for (int idx = tid; idx < MAXDET * (NCLS / 4); idx += 1024) {
        int s = idx / (NCLS / 4), cc = idx % (NCLS / 4);
        float4 v = make_float4(0.f, 0.f, 0.f, 0.f);
        if (s < kc) v = lg4[((size_t)b * NCAND + kept_n[s]) * (NCLS / 4) + cc];
        lgo4[idx] = v;
    }
}

extern "C" void kernel_launch(void* const* d_in, const int* in_sizes, int n_in,
                              void* d_out, int out_size, void* d_ws, size_t ws_size,
                              hipStream_t stream) {
    (void)in_sizes; (void)n_in; (void)out_size; (void)ws_size;
    const float* pred = (const float*)d_in[0];
    const float* logits = (const float*)d_in[1];
    float* out = (float*)d_out;
    char* ws = (char*)d_ws;

    // workspace layout (bytes). score+bx dead after k_topk; M overlays them.
    float* score  = (float*)(ws + 0);                    // 1,612,800
    float* bx     = (float*)(ws + 1612800);              // 6,451,200 (16B aligned)
    int*   cls    = (int*)(ws + 8064000);                // 1,612,800
    ull*   M      = (ull*)(ws + 0);                      // 2,048,000 (overlay on score+bx head)
    int*   cnt    = (int*)(ws + 9676800);                // 1,024 (16 imgs x 64B)
    int*   topidx = (int*)(ws + 9677824);                // 64,000
    float* topsc  = (float*)(ws + 9741824);              // 64,000
    int*   topcls = (int*)(ws + 9805824);                // 64,000
    float* boxes  = (float*)(ws + 9869824);              // 256,000 (16B aligned)
                                                         // total 10,125,824

    const int nrows = BATCH * NCAND;                     // 403200
    k_score<<<nrows / TILE_ROWS, 256, 0, stream>>>(pred, score, bx, cls);
    k_topk<<<BATCH, 1024, 0, stream>>>(score, bx, cls, topidx, topsc, topcls, boxes, cnt);
    k_iou<<<(BATCH * KTOP * 16) / 256, 256, 0, stream>>>(boxes, M);
    k_nms_out<<<BATCH, 1024, 0, stream>>>(M, cnt, logits, topidx, topsc, topcls, boxes, out);
}